// Round 11
// baseline (374.493 us; speedup 1.0000x reference)
//
#include <hip/hip_runtime.h>
#include <hip/hip_fp16.h>

#define NN 50000
#define NE 800000
#define DD 96
#define SVP 100   // padded LDS row stride (floats), conflict-free & 16B-aligned
#define CAP 64    // bucket capacity per node; P(deg>64) ~ 1e-21
#define KCH 12    // phase-B weight K-chunk rows (96/12 = 8 chunks)
#define NCH 8

typedef float f4 __attribute__((ext_vector_type(4)));
typedef float f2 __attribute__((ext_vector_type(2)));
typedef int   i4 __attribute__((ext_vector_type(4)));
typedef _Float16 h4 __attribute__((ext_vector_type(4)));
typedef _Float16 h2 __attribute__((ext_vector_type(2)));

// ---------------------------------------------------------------------------
// Kernel 1: Vp = relu(leaky_relu(V) @ A_w + A_b), stored FP16. Zeroes cnt[].
// 64-row tile, 256 threads, thread = 4 rows x 6 cols.
// ---------------------------------------------------------------------------
__global__ __launch_bounds__(256) void k_vp(
    const float* __restrict__ V, const float* __restrict__ Aw,
    const float* __restrict__ Ab, _Float16* __restrict__ Vp,
    int* __restrict__ cnt)
{
    __shared__ float sW[DD * DD];
    __shared__ float sV[64 * SVP];
    __shared__ float sB[DD];

    const int tid = threadIdx.x;
    const int gt = blockIdx.x * 256 + tid;
    if (gt < NN) cnt[gt] = 0;

    for (int i = tid; i < DD * DD / 4; i += 256)
        reinterpret_cast<f4*>(sW)[i] = reinterpret_cast<const f4*>(Aw)[i];
    if (tid < DD / 4)
        reinterpret_cast<f4*>(sB)[tid] = reinterpret_cast<const f4*>(Ab)[tid];

    const int row0 = blockIdx.x * 64;
    const int nr = min(64, NN - row0);
    for (int i = tid; i < nr * (DD / 4); i += 256) {
        const int r = i / (DD / 4);
        const int c = i % (DD / 4);
        f4 v = reinterpret_cast<const f4*>(V + (size_t)(row0 + r) * DD)[c];
        v[0] = v[0] > 0.f ? v[0] : 0.2f * v[0];
        v[1] = v[1] > 0.f ? v[1] : 0.2f * v[1];
        v[2] = v[2] > 0.f ? v[2] : 0.2f * v[2];
        v[3] = v[3] > 0.f ? v[3] : 0.2f * v[3];
        reinterpret_cast<f4*>(sV + r * SVP)[c] = v;
    }
    __syncthreads();

    const int cg = tid & 15;
    const int rg = tid >> 4;
    const int c0 = cg * 6;
    const int r0 = rg * 4;

    float acc[4][6];
#pragma unroll
    for (int rr = 0; rr < 4; ++rr)
#pragma unroll
        for (int j = 0; j < 6; ++j) acc[rr][j] = sB[c0 + j];

#pragma unroll 4
    for (int k = 0; k < DD; ++k) {
        float x[4];
#pragma unroll
        for (int rr = 0; rr < 4; ++rr) x[rr] = sV[(r0 + rr) * SVP + k];
#pragma unroll
        for (int j = 0; j < 6; ++j) {
            const float w = sW[k * DD + c0 + j];
#pragma unroll
            for (int rr = 0; rr < 4; ++rr)
                acc[rr][j] = fmaf(x[rr], w, acc[rr][j]);
        }
    }

#pragma unroll
    for (int rr = 0; rr < 4; ++rr) {
        const int row = row0 + r0 + rr;
        if (row < NN) {
            h2* vph = reinterpret_cast<h2*>(Vp + (size_t)row * DD);
#pragma unroll
            for (int p = 0; p < 3; ++p) {
                h2 hp;
                hp[0] = (_Float16)fmaxf(acc[rr][2 * p], 0.f);
                hp[1] = (_Float16)fmaxf(acc[rr][2 * p + 1], 0.f);
                vph[c0 / 2 + p] = hp;
            }
        }
    }
}

// ---------------------------------------------------------------------------
// Kernel 2: bucket scatter. aux[d*CAP + pos] = (src, eid, w, 0).
// ---------------------------------------------------------------------------
__global__ __launch_bounds__(256) void k_scatter(
    const int* __restrict__ src, const int* __restrict__ dst,
    const float* __restrict__ ea, int* __restrict__ cnt,
    i4* __restrict__ aux)
{
    const int e = blockIdx.x * 256 + threadIdx.x;
    if (e >= NE) return;
    const int d = dst[e];
    const int pos = atomicAdd(&cnt[d], 1);
    i4 a;
    a.x = src[e];
    a.y = e;
    a.z = __float_as_int(ea[(size_t)e * 4 + 1]);
    a.w = 0;
    if (pos < CAP)
        __builtin_nontemporal_store(a, aux + (size_t)d * CAP + pos);
}

// ---------------------------------------------------------------------------
// Kernel 3: FUSED aggregation + finalize. One block = 32 nodes, 256 threads.
// Phase A: 8 groups x 32 lanes, 8-edge bursts (16 row-loads in flight).
//   E loads NT f4 (read-once); Vp loads FP16 h4 (halved fabric bytes).
// Phase B: 3 GEMMs out of LDS, K=12 weight panels (8 chunks per GEMM).
// LDS 30.8 KB + launch_bounds(256,5) -> 5 blocks/CU (20 waves/CU).
// ---------------------------------------------------------------------------
__global__ __launch_bounds__(256, 5) void k_aggout(
    const _Float16* __restrict__ Vp, const float* __restrict__ E,
    const int* __restrict__ cnt, const i4* __restrict__ aux,
    const float* __restrict__ Vin, const float* __restrict__ Mw,
    const float* __restrict__ Mb, const float* __restrict__ Ww,
    const float* __restrict__ Wb, float* __restrict__ out)
{
    __shared__ float sAgg[32 * SVP];  // 12.8 KB: aggV tile, then a1 in place
    __shared__ float sG[32 * SVP];    // 12.8 KB: G tile, then Vin tile
    __shared__ float sW[KCH * DD];    // 4.6 KB: K=12 weight panel
    __shared__ float sB[DD];
    __shared__ float sS[32];

    const int tid = threadIdx.x;
    const int row0 = blockIdx.x * 32;

    // ================= phase A: aggregate 32 nodes into LDS ===============
    {
        const int grp = tid >> 5;       // 8 groups
        const int gl = tid & 31;
        const bool act = (gl < 24);

        // prefetch: 4 aux chunks + 4 counts, all independent loads
        i4 apre[4];
        int n[4];
#pragma unroll
        for (int i = 0; i < 4; ++i) {
            const int node = row0 + grp * 4 + i;
            const bool ok = (node < NN);
            apre[i] = ok ? __builtin_nontemporal_load(aux + (size_t)node * CAP + gl)
                         : i4{0, 0, 0, 0};
            n[i] = ok ? min(cnt[node], CAP) : 0;
        }

#pragma unroll
        for (int i = 0; i < 4; ++i) {
            const int nl = grp * 4 + i;
            const int node = row0 + nl;
            if (node >= NN) break;

            f4 av = {0.f, 0.f, 0.f, 0.f};
            f4 ag = {0.f, 0.f, 0.f, 0.f};
            float wsum = 0.f;

            i4 a = apre[i];
            const int nfirst = min(n[i], 32);

            int j = 0;
            // ---- 8-edge burst: 16 row-loads in flight
            for (; j + 8 <= nfirst; j += 8) {
                int ss[8], ee[8];
                float ww[8];
#pragma unroll
                for (int q = 0; q < 8; ++q) {
                    ss[q] = __shfl(a.x, j + q, 32);
                    ee[q] = __shfl(a.y, j + q, 32);
                    ww[q] = __shfl(__int_as_float(a.z), j + q, 32);
                }
                f4 Ev[8], Vv[8];
#pragma unroll
                for (int q = 0; q < 8; ++q) {
                    if (act) {
                        Ev[q] = __builtin_nontemporal_load(
                            reinterpret_cast<const f4*>(E + (size_t)ee[q] * DD) + gl);
                        const h4 hv = *(reinterpret_cast<const h4*>(
                            Vp + (size_t)ss[q] * DD) + gl);
                        Vv[q] = f4{(float)hv[0], (float)hv[1],
                                   (float)hv[2], (float)hv[3]};
                    } else {
                        Ev[q] = f4{0, 0, 0, 0};
                        Vv[q] = f4{0, 0, 0, 0};
                    }
                }
#pragma unroll
                for (int q = 0; q < 8; ++q) {
#pragma unroll
                    for (int c = 0; c < 4; ++c) {
                        av[c] = fmaf(ww[q], Vv[q][c], av[c]);
                        ag[c] = fmaf(ww[q], Ev[q][c], ag[c]);
                    }
                    wsum += ww[q];
                }
            }
            // ---- 4-edge burst
            for (; j + 4 <= nfirst; j += 4) {
                int ss[4], ee[4];
                float ww[4];
#pragma unroll
                for (int q = 0; q < 4; ++q) {
                    ss[q] = __shfl(a.x, j + q, 32);
                    ee[q] = __shfl(a.y, j + q, 32);
                    ww[q] = __shfl(__int_as_float(a.z), j + q, 32);
                }
                f4 Ev[4], Vv[4];
#pragma unroll
                for (int q = 0; q < 4; ++q) {
                    if (act) {
                        Ev[q] = __builtin_nontemporal_load(
                            reinterpret_cast<const f4*>(E + (size_t)ee[q] * DD) + gl);
                        const h4 hv = *(reinterpret_cast<const h4*>(
                            Vp + (size_t)ss[q] * DD) + gl);
                        Vv[q] = f4{(float)hv[0], (float)hv[1],
                                   (float)hv[2], (float)hv[3]};
                    } else {
                        Ev[q] = f4{0, 0, 0, 0};
                        Vv[q] = f4{0, 0, 0, 0};
                    }
                }
#pragma unroll
                for (int q = 0; q < 4; ++q) {
#pragma unroll
                    for (int c = 0; c < 4; ++c) {
                        av[c] = fmaf(ww[q], Vv[q][c], av[c]);
                        ag[c] = fmaf(ww[q], Ev[q][c], ag[c]);
                    }
                    wsum += ww[q];
                }
            }
            // ---- scalar tail
            for (; j < nfirst; ++j) {
                const int s0 = __shfl(a.x, j, 32), e0 = __shfl(a.y, j, 32);
                const float w0 = __shfl(__int_as_float(a.z), j, 32);
                f4 E0 = {0, 0, 0, 0}, V0 = {0, 0, 0, 0};
                if (act) {
                    E0 = __builtin_nontemporal_load(
                        reinterpret_cast<const f4*>(E + (size_t)e0 * DD) + gl);
                    const h4 hv = *(reinterpret_cast<const h4*>(
                        Vp + (size_t)s0 * DD) + gl);
                    V0 = f4{(float)hv[0], (float)hv[1], (float)hv[2], (float)hv[3]};
                }
#pragma unroll
                for (int c = 0; c < 4; ++c) {
                    av[c] = fmaf(w0, V0[c], av[c]);
                    ag[c] = fmaf(w0, E0[c], ag[c]);
                }
                wsum += w0;
            }

            // rare tail: degree > 32
            if (n[i] > 32) {
                i4 a2 = __builtin_nontemporal_load(
                    aux + (size_t)node * CAP + 32 + gl);
                const int rem = n[i] - 32;
                for (int jj = 0; jj < rem; ++jj) {
                    const int s0 = __shfl(a2.x, jj, 32), e0 = __shfl(a2.y, jj, 32);
                    const float w0 = __shfl(__int_as_float(a2.z), jj, 32);
                    f4 E0 = {0, 0, 0, 0}, V0 = {0, 0, 0, 0};
                    if (act) {
                        E0 = __builtin_nontemporal_load(
                            reinterpret_cast<const f4*>(E + (size_t)e0 * DD) + gl);
                        const h4 hv = *(reinterpret_cast<const h4*>(
                            Vp + (size_t)s0 * DD) + gl);
                        V0 = f4{(float)hv[0], (float)hv[1], (float)hv[2], (float)hv[3]};
                    }
#pragma unroll
                    for (int c = 0; c < 4; ++c) {
                        av[c] = fmaf(w0, V0[c], av[c]);
                        ag[c] = fmaf(w0, E0[c], ag[c]);
                    }
                    wsum += w0;
                }
            }

            if (act) {
                *reinterpret_cast<f4*>(sAgg + nl * SVP + gl * 4) = av;
                *reinterpret_cast<f4*>(sG + nl * SVP + gl * 4) = ag;
            }
            if (gl == 0) sS[nl] = wsum;
        }
    }
    __syncthreads();

    // ================= phase B: GEMMs out of LDS ==========================
    const int cg = tid & 15;        // 16 col groups of 6
    const int rg = tid >> 4;        // 16 row groups of 2
    const int c0 = cg * 6;
    const int r0 = rg * 2;

    auto loadW = [&](const float* wsrc) {
        for (int i = tid; i < KCH * DD / 4; i += 256)
            reinterpret_cast<f4*>(sW)[i] = reinterpret_cast<const f4*>(wsrc)[i];
    };
    auto loadB = [&](const float* bsrc) {
        if (tid < DD / 4)
            reinterpret_cast<f4*>(sB)[tid] = reinterpret_cast<const f4*>(bsrc)[tid];
    };

    // ---- GEMM1: a1 = sAgg + sG @ Mw + sS * Mb   (8 K-chunks of 12)
    loadW(Mw); loadB(Mb);
    __syncthreads();

    float a[2][6];
#pragma unroll
    for (int rr = 0; rr < 2; ++rr) {
        const float sv = sS[r0 + rr];
#pragma unroll
        for (int j = 0; j < 6; ++j)
            a[rr][j] = sAgg[(r0 + rr) * SVP + c0 + j] + sv * sB[c0 + j];
    }
#pragma unroll
    for (int ch = 0; ch < NCH; ++ch) {
        if (ch) {
            __syncthreads();
            loadW(Mw + ch * KCH * DD);
            __syncthreads();
        }
        const int kb = ch * KCH;
#pragma unroll
        for (int k = 0; k < KCH; ++k) {
            const float x0 = sG[r0 * SVP + kb + k];
            const float x1 = sG[(r0 + 1) * SVP + kb + k];
#pragma unroll
            for (int j = 0; j < 6; ++j) {
                const float w = sW[k * DD + c0 + j];
                a[0][j] = fmaf(x0, w, a[0][j]);
                a[1][j] = fmaf(x1, w, a[1][j]);
            }
        }
    }
    __syncthreads();
#pragma unroll
    for (int rr = 0; rr < 2; ++rr)
#pragma unroll
        for (int j = 0; j < 6; ++j)
            sAgg[(r0 + rr) * SVP + c0 + j] = a[rr][j];

    // sG free: load Vin tile for GEMM3 (NT, read-once)
    {
        const int nr = min(32, NN - row0);
        for (int i = tid; i < nr * (DD / 4); i += 256) {
            const int r = i / (DD / 4);
            const int c = i % (DD / 4);
            reinterpret_cast<f4*>(sG + r * SVP)[c] = __builtin_nontemporal_load(
                reinterpret_cast<const f4*>(Vin + (size_t)(row0 + r) * DD) + c);
        }
    }

    // ---- GEMM2: o = Wb + a1 @ W1
    loadW(Ww); loadB(Wb);
    __syncthreads();

    float o[2][6];
#pragma unroll
    for (int rr = 0; rr < 2; ++rr)
#pragma unroll
        for (int j = 0; j < 6; ++j) o[rr][j] = sB[c0 + j];
#pragma unroll
    for (int ch = 0; ch < NCH; ++ch) {
        if (ch) {
            __syncthreads();
            loadW(Ww + ch * KCH * DD);
            __syncthreads();
        }
        const int kb = ch * KCH;
#pragma unroll
        for (int k = 0; k < KCH; ++k) {
            const float x0 = sAgg[r0 * SVP + kb + k];
            const float x1 = sAgg[(r0 + 1) * SVP + kb + k];
#pragma unroll
            for (int j = 0; j < 6; ++j) {
                const float w = sW[k * DD + c0 + j];
                o[0][j] = fmaf(x0, w, o[0][j]);
                o[1][j] = fmaf(x1, w, o[1][j]);
            }
        }
    }

    // ---- GEMM3: o += Vin @ W2
#pragma unroll
    for (int ch = 0; ch < NCH; ++ch) {
        __syncthreads();
        loadW(Ww + (size_t)(DD + ch * KCH) * DD);
        __syncthreads();
        const int kb = ch * KCH;
#pragma unroll
        for (int k = 0; k < KCH; ++k) {
            const float x0 = sG[r0 * SVP + kb + k];
            const float x1 = sG[(r0 + 1) * SVP + kb + k];
#pragma unroll
            for (int j = 0; j < 6; ++j) {
                const float w = sW[k * DD + c0 + j];
                o[0][j] = fmaf(x0, w, o[0][j]);
                o[1][j] = fmaf(x1, w, o[1][j]);
            }
        }
    }

#pragma unroll
    for (int rr = 0; rr < 2; ++rr) {
        const int row = row0 + r0 + rr;
        if (row < NN) {
            float* op = out + (size_t)row * DD + c0;
#pragma unroll
            for (int p = 0; p < 3; ++p) {
                f2 v;
                v[0] = fmaxf(o[rr][2 * p], 0.f);
                v[1] = fmaxf(o[rr][2 * p + 1], 0.f);
                __builtin_nontemporal_store(v, reinterpret_cast<f2*>(op) + p);
            }
        }
    }
}

// ---------------------------------------------------------------------------
extern "C" void kernel_launch(void* const* d_in, const int* in_sizes, int n_in,
                              void* d_out, int out_size, void* d_ws, size_t ws_size,
                              hipStream_t stream)
{
    const float* V   = (const float*)d_in[0];
    const float* Vin = (const float*)d_in[1];
    const float* E   = (const float*)d_in[2];
    const float* ea  = (const float*)d_in[3];
    const int*   src = (const int*)d_in[4];
    const int*   dst = (const int*)d_in[5];
    const float* Aw  = (const float*)d_in[6];
    const float* Ab  = (const float*)d_in[7];
    const float* Mw  = (const float*)d_in[8];
    const float* Mb  = (const float*)d_in[9];
    const float* Ww  = (const float*)d_in[10];
    const float* Wb  = (const float*)d_in[11];
    float* out = (float*)d_out;

    // workspace layout
    _Float16* Vp = (_Float16*)d_ws;                          // NN*DD fp16 (9.6 MB)
    int* cnt = (int*)((char*)d_ws + (size_t)NN * DD * 2);    // NN ints
    size_t aux_byte = (size_t)NN * DD * 2 + (size_t)NN * 4;
    aux_byte = (aux_byte + 15) & ~(size_t)15;                // 16B align
    i4* aux = (i4*)((char*)d_ws + aux_byte);                 // NN*CAP i4 (51.2 MB)

    k_vp<<<(NN + 63) / 64, 256, 0, stream>>>(V, Aw, Ab, Vp, cnt);
    k_scatter<<<(NE + 255) / 256, 256, 0, stream>>>(src, dst, ea, cnt, aux);
    k_aggout<<<(NN + 31) / 32, 256, 0, stream>>>(Vp, E, cnt, aux, Vin,
                                                 Mw, Mb, Ww, Wb, out);
}

// Round 12
// 270.870 us; speedup vs baseline: 1.3826x; 1.3826x over previous
//
#include <hip/hip_runtime.h>
#include <hip/hip_bf16.h>

#define NN 50000
#define NE 800000
#define DD 96
#define SVP 100   // padded LDS row stride (floats): breaks phase-B bank conflicts
#define CAP 64    // bucket capacity per node; P(deg>64) ~ 1e-21

typedef float f4 __attribute__((ext_vector_type(4)));
typedef int   i4 __attribute__((ext_vector_type(4)));
typedef const __attribute__((address_space(1))) float gfloat_t;
typedef __attribute__((address_space(3))) float lfloat_t;

// ---------------------------------------------------------------------------
// Kernel 1: Vp = relu(leaky_relu(V) @ A_w + A_b) (fp32). Zeroes cnt[].
// ---------------------------------------------------------------------------
__global__ __launch_bounds__(256) void k_vp(
    const float* __restrict__ V, const float* __restrict__ Aw,
    const float* __restrict__ Ab, float* __restrict__ Vp,
    int* __restrict__ cnt)
{
    __shared__ float sW[DD * DD];
    __shared__ float sV[64 * SVP];
    __shared__ float sB[DD];

    const int tid = threadIdx.x;
    const int gt = blockIdx.x * 256 + tid;
    if (gt < NN) cnt[gt] = 0;

    for (int i = tid; i < DD * DD / 4; i += 256)
        reinterpret_cast<f4*>(sW)[i] = reinterpret_cast<const f4*>(Aw)[i];
    if (tid < DD / 4)
        reinterpret_cast<f4*>(sB)[tid] = reinterpret_cast<const f4*>(Ab)[tid];

    const int row0 = blockIdx.x * 64;
    const int nr = min(64, NN - row0);
    for (int i = tid; i < nr * (DD / 4); i += 256) {
        const int r = i / (DD / 4);
        const int c = i % (DD / 4);
        f4 v = reinterpret_cast<const f4*>(V + (size_t)(row0 + r) * DD)[c];
        v[0] = v[0] > 0.f ? v[0] : 0.2f * v[0];
        v[1] = v[1] > 0.f ? v[1] : 0.2f * v[1];
        v[2] = v[2] > 0.f ? v[2] : 0.2f * v[2];
        v[3] = v[3] > 0.f ? v[3] : 0.2f * v[3];
        reinterpret_cast<f4*>(sV + r * SVP)[c] = v;
    }
    __syncthreads();

    const int cg = tid & 15;
    const int rg = tid >> 4;
    const int c0 = cg * 6;
    const int r0 = rg * 4;

    float acc[4][6];
#pragma unroll
    for (int rr = 0; rr < 4; ++rr)
#pragma unroll
        for (int j = 0; j < 6; ++j) acc[rr][j] = sB[c0 + j];

#pragma unroll 4
    for (int k = 0; k < DD; ++k) {
        float x[4];
#pragma unroll
        for (int rr = 0; rr < 4; ++rr) x[rr] = sV[(r0 + rr) * SVP + k];
#pragma unroll
        for (int j = 0; j < 6; ++j) {
            const float w = sW[k * DD + c0 + j];
#pragma unroll
            for (int rr = 0; rr < 4; ++rr)
                acc[rr][j] = fmaf(x[rr], w, acc[rr][j]);
        }
    }

#pragma unroll
    for (int rr = 0; rr < 4; ++rr) {
        const int row = row0 + r0 + rr;
        if (row < NN) {
#pragma unroll
            for (int j = 0; j < 6; ++j)
                Vp[(size_t)row * DD + c0 + j] = fmaxf(acc[rr][j], 0.f);
        }
    }
}

// ---------------------------------------------------------------------------
// Kernel 2: bucket scatter. aux[d*CAP + pos] = (src, eid, w, 0).
// ---------------------------------------------------------------------------
__global__ __launch_bounds__(256) void k_scatter(
    const int* __restrict__ src, const int* __restrict__ dst,
    const float* __restrict__ ea, int* __restrict__ cnt,
    i4* __restrict__ aux)
{
    const int e = blockIdx.x * 256 + threadIdx.x;
    if (e >= NE) return;
    const int d = dst[e];
    const int pos = atomicAdd(&cnt[d], 1);
    i4 a;
    a.x = src[e];
    a.y = e;
    a.z = __float_as_int(ea[(size_t)e * 4 + 1]);
    a.w = 0;
    if (pos < CAP)
        __builtin_nontemporal_store(a, aux + (size_t)d * CAP + pos);
}

// ---------------------------------------------------------------------------
// Kernel 3: FUSED aggregation + finalize. Block = 32 nodes, 256 threads.
// Phase A: one WAVE per node. E rows DMA'd to LDS via global_load_lds
//   (8 rows = 3 x 1KB instr, double-buffered, counted vmcnt(3) — VGPR-free
//   in-flight). Vp rows as 4-deep VGPR loads (L2/MALL-resident).
//   Clamped addresses keep instruction counts static (sound vmcnt immediates).
// Phase B: 3 GEMMs out of LDS, K=32 weight panels (R9 structure).
// LDS: sAgg 12.8K + sG 12.8K + staging 24K (aliased by sW in phase B) ~ 50KB
//   -> 3 blocks/CU, VGPR budget ~170.
// ---------------------------------------------------------------------------
__global__ __launch_bounds__(256) void k_aggout(
    const float* __restrict__ Vp, const float* __restrict__ E,
    const int* __restrict__ cnt, const i4* __restrict__ aux,
    const float* __restrict__ Vin, const float* __restrict__ Mw,
    const float* __restrict__ Mb, const float* __restrict__ Ww,
    const float* __restrict__ Wb, float* __restrict__ out)
{
    __shared__ float sAgg[32 * SVP];      // 12.8 KB
    __shared__ float sG[32 * SVP];        // 12.8 KB
    __shared__ float sStage[4 * 2 * 768]; // 24 KB: 4 waves x 2 bufs x 3KB; sW alias
    __shared__ float sB[DD];
    __shared__ float sS[32];

    const int tid = threadIdx.x;
    const int lane = tid & 63;
    const int wid = tid >> 6;             // 4 waves
    const int row0 = blockIdx.x * 32;

    // ================= phase A: wave-per-node aggregation =================
    {
        const int c4l = lane % 24;                 // f4 column index
        const int rsel = (lane >= 24 && lane < 48) ? 1 : 0;
        const int stgwave = wid * 1536;            // floats

        for (int i = 0; i < 8; ++i) {
            const int nl = wid * 8 + i;
            const int node = row0 + nl;
            if (node >= NN) break;                 // wave-uniform

            const i4 a = __builtin_nontemporal_load(aux + (size_t)node * CAP + lane);
            const int n = min(cnt[node], CAP);

            if (n == 0) {
                if (lane < 24) {
                    f4 z = {0.f, 0.f, 0.f, 0.f};
                    *reinterpret_cast<f4*>(sAgg + nl * SVP + lane * 4) = z;
                    *reinterpret_cast<f4*>(sG + nl * SVP + lane * 4) = z;
                }
                if (lane == 0) sS[nl] = 0.f;
                continue;
            }

            const int nm1 = n - 1;
            const float wz = __int_as_float(a.z);
            const int nsc = (n + 7) >> 3;

            f4 av = {0.f, 0.f, 0.f, 0.f};
            f4 ag = {0.f, 0.f, 0.f, 0.f};

            // ---- DMA one 8-row chunk of E into staging buf b (3 x 1KB)
            auto STAGE = [&](int sc, int b) {
                const int base = stgwave + b * 768;     // floats
#pragma unroll
                for (int k = 0; k < 3; ++k) {
                    const int m = k * 64 + lane;        // 16B-unit index, 0..191
                    const int row = m / 24;             // 0..7
                    const int col = m - row * 24;
                    const int gr = min(sc * 8 + row, nm1);  // clamp: static count
                    const int eid = __shfl(a.y, gr, 64);
                    __builtin_amdgcn_global_load_lds(
                        (gfloat_t*)(E + (size_t)eid * DD + col * 4),
                        (lfloat_t*)(sStage + base + k * 256),
                        16, 0, 0);
                }
            };

            STAGE(0, 0);

            for (int sc = 0; sc < nsc; ++sc) {
                // ---- Vp loads for this chunk (4 x 16B, unconditional)
                f4 Vv[4];
                float wr[4];
#pragma unroll
                for (int q = 0; q < 4; ++q) {
                    const int r = sc * 8 + q * 2 + rsel;
                    const int rc = min(r, nm1);
                    const int sid = __shfl(a.x, rc, 64);
                    const float w = __shfl(wz, rc, 64);
                    wr[q] = (r < n) ? w : 0.f;
                    Vv[q] = *(reinterpret_cast<const f4*>(Vp + (size_t)sid * DD) + c4l);
                }

                if (sc + 1 < nsc) {
                    STAGE(sc + 1, (sc + 1) & 1);
                    asm volatile("s_waitcnt vmcnt(3)" ::: "memory");
                } else {
                    asm volatile("s_waitcnt vmcnt(0)" ::: "memory");
                }
                __builtin_amdgcn_sched_barrier(0);

                // ---- FMA from staged E (LDS) + Vp (VGPR)
                const float* stg = sStage + stgwave + (sc & 1) * 768;
#pragma unroll
                for (int q = 0; q < 4; ++q) {
                    const int rl = q * 2 + rsel;
                    const f4 Ev = *reinterpret_cast<const f4*>(stg + rl * 96 + c4l * 4);
#pragma unroll
                    for (int c = 0; c < 4; ++c) {
                        av[c] = fmaf(wr[q], Vv[q][c], av[c]);
                        ag[c] = fmaf(wr[q], Ev[c], ag[c]);
                    }
                }
            }

            // ---- wsum: reduce w over lanes < n
            float wl = (lane < n) ? wz : 0.f;
#pragma unroll
            for (int d = 1; d < 64; d <<= 1)
                wl += __shfl_xor(wl, d, 64);

            // ---- combine odd-row half (lanes 24-47) into lanes 0-23, store
            f4 av2, ag2;
#pragma unroll
            for (int c = 0; c < 4; ++c) {
                av2[c] = __shfl(av[c], (lane & 31) + 24, 64);
                ag2[c] = __shfl(ag[c], (lane & 31) + 24, 64);
            }
            if (lane < 24) {
                f4 avt, agt;
#pragma unroll
                for (int c = 0; c < 4; ++c) {
                    avt[c] = av[c] + av2[c];
                    agt[c] = ag[c] + ag2[c];
                }
                *reinterpret_cast<f4*>(sAgg + nl * SVP + lane * 4) = avt;
                *reinterpret_cast<f4*>(sG + nl * SVP + lane * 4) = agt;
            }
            if (lane == 0) sS[nl] = wl;
        }
    }
    __syncthreads();

    // ================= phase B: GEMMs out of LDS (R9 structure) ===========
    float* const sW = sStage;       // staging dead; alias as weight panel
    const int cg = tid & 15;        // 16 col groups of 6
    const int rg = tid >> 4;        // 16 row groups of 2
    const int c0 = cg * 6;
    const int r0 = rg * 2;

    auto loadW = [&](const float* wsrc) {
        for (int i = tid; i < 32 * DD / 4; i += 256)
            reinterpret_cast<f4*>(sW)[i] = reinterpret_cast<const f4*>(wsrc)[i];
    };
    auto loadB = [&](const float* bsrc) {
        if (tid < DD / 4)
            reinterpret_cast<f4*>(sB)[tid] = reinterpret_cast<const f4*>(bsrc)[tid];
    };

    // ---- GEMM1: a1 = sAgg + sG @ Mw + sS * Mb   (3 K-chunks of 32)
    loadW(Mw); loadB(Mb);
    __syncthreads();

    float a[2][6];
#pragma unroll
    for (int rr = 0; rr < 2; ++rr) {
        const float sv = sS[r0 + rr];
#pragma unroll
        for (int j = 0; j < 6; ++j)
            a[rr][j] = sAgg[(r0 + rr) * SVP + c0 + j] + sv * sB[c0 + j];
    }
#pragma unroll
    for (int ch = 0; ch < 3; ++ch) {
        if (ch) {
            __syncthreads();
            loadW(Mw + ch * 32 * DD);
            __syncthreads();
        }
        const int kb = ch * 32;
#pragma unroll 4
        for (int k = 0; k < 32; ++k) {
            const float x0 = sG[r0 * SVP + kb + k];
            const float x1 = sG[(r0 + 1) * SVP + kb + k];
#pragma unroll
            for (int j = 0; j < 6; ++j) {
                const float w = sW[k * DD + c0 + j];
                a[0][j] = fmaf(x0, w, a[0][j]);
                a[1][j] = fmaf(x1, w, a[1][j]);
            }
        }
    }
    __syncthreads();
#pragma unroll
    for (int rr = 0; rr < 2; ++rr)
#pragma unroll
        for (int j = 0; j < 6; ++j)
            sAgg[(r0 + rr) * SVP + c0 + j] = a[rr][j];

    // sG free: load Vin tile for GEMM3
    {
        const int nr = min(32, NN - row0);
        __syncthreads();
        for (int i = tid; i < nr * (DD / 4); i += 256) {
            const int r = i / (DD / 4);
            const int c = i % (DD / 4);
            reinterpret_cast<f4*>(sG + r * SVP)[c] =
                reinterpret_cast<const f4*>(Vin + (size_t)(row0 + r) * DD)[c];
        }
    }

    // ---- GEMM2: o = Wb + a1 @ W1
    loadW(Ww); loadB(Wb);
    __syncthreads();

    float o[2][6];
#pragma unroll
    for (int rr = 0; rr < 2; ++rr)
#pragma unroll
        for (int j = 0; j < 6; ++j) o[rr][j] = sB[c0 + j];
#pragma unroll
    for (int ch = 0; ch < 3; ++ch) {
        if (ch) {
            __syncthreads();
            loadW(Ww + ch * 32 * DD);
            __syncthreads();
        }
        const int kb = ch * 32;
#pragma unroll 4
        for (int k = 0; k < 32; ++k) {
            const float x0 = sAgg[r0 * SVP + kb + k];
            const float x1 = sAgg[(r0 + 1) * SVP + kb + k];
#pragma unroll
            for (int j = 0; j < 6; ++j) {
                const float w = sW[k * DD + c0 + j];
                o[0][j] = fmaf(x0, w, o[0][j]);
                o[1][j] = fmaf(x1, w, o[1][j]);
            }
        }
    }

    // ---- GEMM3: o += Vin @ W2
#pragma unroll
    for (int ch = 0; ch < 3; ++ch) {
        __syncthreads();
        loadW(Ww + (size_t)(96 + ch * 32) * DD);
        __syncthreads();
        const int kb = ch * 32;
#pragma unroll 4
        for (int k = 0; k < 32; ++k) {
            const float x0 = sG[r0 * SVP + kb + k];
            const float x1 = sG[(r0 + 1) * SVP + kb + k];
#pragma unroll
            for (int j = 0; j < 6; ++j) {
                const float w = sW[k * DD + c0 + j];
                o[0][j] = fmaf(x0, w, o[0][j]);
                o[1][j] = fmaf(x1, w, o[1][j]);
            }
        }
    }

#pragma unroll
    for (int rr = 0; rr < 2; ++rr) {
        const int row = row0 + r0 + rr;
        if (row < NN) {
#pragma unroll
            for (int j = 0; j < 6; ++j)
                out[(size_t)row * DD + c0 + j] = fmaxf(o[rr][j], 0.f);
        }
    }
}

// ---------------------------------------------------------------------------
extern "C" void kernel_launch(void* const* d_in, const int* in_sizes, int n_in,
                              void* d_out, int out_size, void* d_ws, size_t ws_size,
                              hipStream_t stream)
{
    const float* V   = (const float*)d_in[0];
    const float* Vin = (const float*)d_in[1];
    const float* E   = (const float*)d_in[2];
    const float* ea  = (const float*)d_in[3];
    const int*   src = (const int*)d_in[4];
    const int*   dst = (const int*)d_in[5];
    const float* Aw  = (const float*)d_in[6];
    const float* Ab  = (const float*)d_in[7];
    const float* Mw  = (const float*)d_in[8];
    const float* Mb  = (const float*)d_in[9];
    const float* Ww  = (const float*)d_in[10];
    const float* Wb  = (const float*)d_in[11];
    float* out = (float*)d_out;

    // workspace layout
    float* Vp  = (float*)d_ws;                     // NN*DD fp32
    int*   cnt = (int*)(Vp + (size_t)NN * DD);     // NN ints
    size_t aux_off = (size_t)NN * DD + NN;
    aux_off = (aux_off + 3) & ~(size_t)3;          // 16B align
    i4*    aux = (i4*)((float*)d_ws + aux_off);    // NN*CAP i4 (51.2 MB)

    k_vp<<<(NN + 63) / 64, 256, 0, stream>>>(V, Aw, Ab, Vp, cnt);
    k_scatter<<<(NE + 255) / 256, 256, 0, stream>>>(src, dst, ea, cnt, aux);
    k_aggout<<<(NN + 31) / 32, 256, 0, stream>>>(Vp, E, cnt, aux, Vin,
                                                 Mw, Mb, Ww, Wb, out);
}

// Round 13
// 218.942 us; speedup vs baseline: 1.7105x; 1.2372x over previous
//
#include <hip/hip_runtime.h>
#include <hip/hip_bf16.h>

#define NN 50000
#define NE 800000
#define DD 96
#define SVP 100   // padded LDS row stride (floats)
#define CAP 64    // bucket capacity per node; P(deg>64) ~ 1e-21

typedef float f4 __attribute__((ext_vector_type(4)));
typedef int   i4 __attribute__((ext_vector_type(4)));

// ---------------------------------------------------------------------------
// Kernel 1 (fused): per block — (a) scatter a 1024-edge chunk into buckets,
// (b) Vp tile GEMM: Vp = relu(leaky_relu(V) @ A_w + A_b) for 64 rows.
// Scatter (memory/atomic-bound) and GEMM (VALU/LDS-bound) pipeline across
// blocks at different phases on the same CU. cnt pre-zeroed by memsetAsync.
// ---------------------------------------------------------------------------
__global__ __launch_bounds__(256) void k_vpscat(
    const float* __restrict__ V, const float* __restrict__ Aw,
    const float* __restrict__ Ab, float* __restrict__ Vp,
    const int* __restrict__ src, const int* __restrict__ dst,
    const float* __restrict__ ea, int* __restrict__ cnt,
    i4* __restrict__ aux)
{
    __shared__ float sW[DD * DD];
    __shared__ float sV[64 * SVP];
    __shared__ float sB[DD];

    const int tid = threadIdx.x;

    // ---- (a) scatter: 4 edges per thread
    const int ebase = blockIdx.x * 1024;
#pragma unroll
    for (int k = 0; k < 4; ++k) {
        const int e = ebase + k * 256 + tid;
        if (e < NE) {
            const int d = dst[e];
            const int pos = atomicAdd(&cnt[d], 1);
            const f4 eav = *reinterpret_cast<const f4*>(ea + (size_t)e * 4);
            i4 a;
            a.x = src[e];
            a.y = e;
            a.z = __float_as_int(eav[1]);
            a.w = 0;
            if (pos < CAP)
                __builtin_nontemporal_store(a, aux + (size_t)d * CAP + pos);
        }
    }

    // ---- (b) Vp tile GEMM
    for (int i = tid; i < DD * DD / 4; i += 256)
        reinterpret_cast<f4*>(sW)[i] = reinterpret_cast<const f4*>(Aw)[i];
    if (tid < DD / 4)
        reinterpret_cast<f4*>(sB)[tid] = reinterpret_cast<const f4*>(Ab)[tid];

    const int row0 = blockIdx.x * 64;
    const int nr = min(64, NN - row0);
    for (int i = tid; i < nr * (DD / 4); i += 256) {
        const int r = i / (DD / 4);
        const int c = i % (DD / 4);
        f4 v = reinterpret_cast<const f4*>(V + (size_t)(row0 + r) * DD)[c];
        v[0] = v[0] > 0.f ? v[0] : 0.2f * v[0];
        v[1] = v[1] > 0.f ? v[1] : 0.2f * v[1];
        v[2] = v[2] > 0.f ? v[2] : 0.2f * v[2];
        v[3] = v[3] > 0.f ? v[3] : 0.2f * v[3];
        reinterpret_cast<f4*>(sV + r * SVP)[c] = v;
    }
    __syncthreads();

    if (row0 >= NN) return;

    const int cg = tid & 15;
    const int rg = tid >> 4;
    const int c0 = cg * 6;
    const int r0 = rg * 4;

    float acc[4][6];
#pragma unroll
    for (int rr = 0; rr < 4; ++rr)
#pragma unroll
        for (int j = 0; j < 6; ++j) acc[rr][j] = sB[c0 + j];

#pragma unroll 4
    for (int k = 0; k < DD; ++k) {
        float x[4];
#pragma unroll
        for (int rr = 0; rr < 4; ++rr) x[rr] = sV[(r0 + rr) * SVP + k];
#pragma unroll
        for (int j = 0; j < 6; ++j) {
            const float w = sW[k * DD + c0 + j];
#pragma unroll
            for (int rr = 0; rr < 4; ++rr)
                acc[rr][j] = fmaf(x[rr], w, acc[rr][j]);
        }
    }

#pragma unroll
    for (int rr = 0; rr < 4; ++rr) {
        const int row = row0 + r0 + rr;
        if (row < NN) {
#pragma unroll
            for (int j = 0; j < 6; ++j)
                Vp[(size_t)row * DD + c0 + j] = fmaxf(acc[rr][j], 0.f);
        }
    }
}

// ---------------------------------------------------------------------------
// Kernel 2: FUSED aggregation + finalize (R9 verbatim — measured best).
// One block = 32 nodes, 256 threads.
// Phase A: 8 groups x 32 lanes, 8-edge bursts (16 row-loads in flight).
// Phase B: 3 GEMMs out of LDS, K=32 weight panels.
// LDS 38.4 KB + launch_bounds(256,4) -> 4 blocks/CU.
// ---------------------------------------------------------------------------
__global__ __launch_bounds__(256, 4) void k_aggout(
    const float* __restrict__ Vp, const float* __restrict__ E,
    const int* __restrict__ cnt, const i4* __restrict__ aux,
    const float* __restrict__ Vin, const float* __restrict__ Mw,
    const float* __restrict__ Mb, const float* __restrict__ Ww,
    const float* __restrict__ Wb, float* __restrict__ out)
{
    __shared__ float sAgg[32 * SVP];  // 12.8 KB: aggV tile, then a1 in place
    __shared__ float sG[32 * SVP];    // 12.8 KB: G tile, then Vin tile
    __shared__ float sW[32 * DD];     // 12.3 KB: K=32 weight panel
    __shared__ float sB[DD];
    __shared__ float sS[32];

    const int tid = threadIdx.x;
    const int row0 = blockIdx.x * 32;

    // ================= phase A: aggregate 32 nodes into LDS ===============
    {
        const int grp = tid >> 5;       // 8 groups
        const int gl = tid & 31;
        const bool act = (gl < 24);

        // prefetch: 4 aux chunks + 4 counts, all independent loads
        i4 apre[4];
        int n[4];
#pragma unroll
        for (int i = 0; i < 4; ++i) {
            const int node = row0 + grp * 4 + i;
            const bool ok = (node < NN);
            apre[i] = ok ? __builtin_nontemporal_load(aux + (size_t)node * CAP + gl)
                         : i4{0, 0, 0, 0};
            n[i] = ok ? min(cnt[node], CAP) : 0;
        }

#pragma unroll
        for (int i = 0; i < 4; ++i) {
            const int nl = grp * 4 + i;
            const int node = row0 + nl;
            if (node >= NN) break;

            f4 av = {0.f, 0.f, 0.f, 0.f};
            f4 ag = {0.f, 0.f, 0.f, 0.f};
            float wsum = 0.f;

            i4 a = apre[i];
            const int nfirst = min(n[i], 32);

            int j = 0;
            // ---- 8-edge burst: 16 row-loads in flight
            for (; j + 8 <= nfirst; j += 8) {
                int ss[8], ee[8];
                float ww[8];
#pragma unroll
                for (int q = 0; q < 8; ++q) {
                    ss[q] = __shfl(a.x, j + q, 32);
                    ee[q] = __shfl(a.y, j + q, 32);
                    ww[q] = __shfl(__int_as_float(a.z), j + q, 32);
                }
                f4 Ev[8], Vv[8];
#pragma unroll
                for (int q = 0; q < 8; ++q) {
                    if (act) {
                        Ev[q] = __builtin_nontemporal_load(
                            reinterpret_cast<const f4*>(E + (size_t)ee[q] * DD) + gl);
                        Vv[q] = *(reinterpret_cast<const f4*>(Vp + (size_t)ss[q] * DD) + gl);
                    } else {
                        Ev[q] = f4{0, 0, 0, 0};
                        Vv[q] = f4{0, 0, 0, 0};
                    }
                }
#pragma unroll
                for (int q = 0; q < 8; ++q) {
#pragma unroll
                    for (int c = 0; c < 4; ++c) {
                        av[c] = fmaf(ww[q], Vv[q][c], av[c]);
                        ag[c] = fmaf(ww[q], Ev[q][c], ag[c]);
                    }
                    wsum += ww[q];
                }
            }
            // ---- 4-edge burst
            for (; j + 4 <= nfirst; j += 4) {
                int ss[4], ee[4];
                float ww[4];
#pragma unroll
                for (int q = 0; q < 4; ++q) {
                    ss[q] = __shfl(a.x, j + q, 32);
                    ee[q] = __shfl(a.y, j + q, 32);
                    ww[q] = __shfl(__int_as_float(a.z), j + q, 32);
                }
                f4 Ev[4], Vv[4];
#pragma unroll
                for (int q = 0; q < 4; ++q) {
                    if (act) {
                        Ev[q] = __builtin_nontemporal_load(
                            reinterpret_cast<const f4*>(E + (size_t)ee[q] * DD) + gl);
                        Vv[q] = *(reinterpret_cast<const f4*>(Vp + (size_t)ss[q] * DD) + gl);
                    } else {
                        Ev[q] = f4{0, 0, 0, 0};
                        Vv[q] = f4{0, 0, 0, 0};
                    }
                }
#pragma unroll
                for (int q = 0; q < 4; ++q) {
#pragma unroll
                    for (int c = 0; c < 4; ++c) {
                        av[c] = fmaf(ww[q], Vv[q][c], av[c]);
                        ag[c] = fmaf(ww[q], Ev[q][c], ag[c]);
                    }
                    wsum += ww[q];
                }
            }
            // ---- scalar tail
            for (; j < nfirst; ++j) {
                const int s0 = __shfl(a.x, j, 32), e0 = __shfl(a.y, j, 32);
                const float w0 = __shfl(__int_as_float(a.z), j, 32);
                f4 E0 = {0, 0, 0, 0}, V0 = {0, 0, 0, 0};
                if (act) {
                    E0 = __builtin_nontemporal_load(
                        reinterpret_cast<const f4*>(E + (size_t)e0 * DD) + gl);
                    V0 = *(reinterpret_cast<const f4*>(Vp + (size_t)s0 * DD) + gl);
                }
#pragma unroll
                for (int c = 0; c < 4; ++c) {
                    av[c] = fmaf(w0, V0[c], av[c]);
                    ag[c] = fmaf(w0, E0[c], ag[c]);
                }
                wsum += w0;
            }

            // rare tail: degree > 32
            if (n[i] > 32) {
                i4 a2 = __builtin_nontemporal_load(
                    aux + (size_t)node * CAP + 32 + gl);
                const int rem = n[i] - 32;
                for (int jj = 0; jj < rem; ++jj) {
                    const int s0 = __shfl(a2.x, jj, 32), e0 = __shfl(a2.y, jj, 32);
                    const float w0 = __shfl(__int_as_float(a2.z), jj, 32);
                    f4 E0 = {0, 0, 0, 0}, V0 = {0, 0, 0, 0};
                    if (act) {
                        E0 = __builtin_nontemporal_load(
                            reinterpret_cast<const f4*>(E + (size_t)e0 * DD) + gl);
                        V0 = *(reinterpret_cast<const f4*>(Vp + (size_t)s0 * DD) + gl);
                    }
#pragma unroll
                    for (int c = 0; c < 4; ++c) {
                        av[c] = fmaf(w0, V0[c], av[c]);
                        ag[c] = fmaf(w0, E0[c], ag[c]);
                    }
                    wsum += w0;
                }
            }

            if (act) {
                *reinterpret_cast<f4*>(sAgg + nl * SVP + gl * 4) = av;
                *reinterpret_cast<f4*>(sG + nl * SVP + gl * 4) = ag;
            }
            if (gl == 0) sS[nl] = wsum;
        }
    }
    __syncthreads();

    // ================= phase B: GEMMs out of LDS ==========================
    const int cg = tid & 15;        // 16 col groups of 6
    const int rg = tid >> 4;        // 16 row groups of 2
    const int c0 = cg * 6;
    const int r0 = rg * 2;

    auto loadW = [&](const float* wsrc) {
        for (int i = tid; i < 32 * DD / 4; i += 256)
            reinterpret_cast<f4*>(sW)[i] = reinterpret_cast<const f4*>(wsrc)[i];
    };
    auto loadB = [&](const float* bsrc) {
        if (tid < DD / 4)
            reinterpret_cast<f4*>(sB)[tid] = reinterpret_cast<const f4*>(bsrc)[tid];
    };

    // ---- GEMM1: a1 = sAgg + sG @ Mw + sS * Mb   (K chunks of 32)
    loadW(Mw); loadB(Mb);
    __syncthreads();

    float a[2][6];
#pragma unroll
    for (int rr = 0; rr < 2; ++rr) {
        const float sv = sS[r0 + rr];
#pragma unroll
        for (int j = 0; j < 6; ++j)
            a[rr][j] = sAgg[(r0 + rr) * SVP + c0 + j] + sv * sB[c0 + j];
    }
#pragma unroll
    for (int ch = 0; ch < 3; ++ch) {
        if (ch) {
            __syncthreads();
            loadW(Mw + ch * 32 * DD);
            __syncthreads();
        }
        const int kb = ch * 32;
#pragma unroll 4
        for (int k = 0; k < 32; ++k) {
            const float x0 = sG[r0 * SVP + kb + k];
            const float x1 = sG[(r0 + 1) * SVP + kb + k];
#pragma unroll
            for (int j = 0; j < 6; ++j) {
                const float w = sW[k * DD + c0 + j];
                a[0][j] = fmaf(x0, w, a[0][j]);
                a[1][j] = fmaf(x1, w, a[1][j]);
            }
        }
    }
    __syncthreads();
#pragma unroll
    for (int rr = 0; rr < 2; ++rr)
#pragma unroll
        for (int j = 0; j < 6; ++j)
            sAgg[(r0 + rr) * SVP + c0 + j] = a[rr][j];

    // sG free: load Vin tile for GEMM3
    {
        const int nr = min(32, NN - row0);
        __syncthreads();
        for (int i = tid; i < nr * (DD / 4); i += 256) {
            const int r = i / (DD / 4);
            const int c = i % (DD / 4);
            reinterpret_cast<f4*>(sG + r * SVP)[c] =
                reinterpret_cast<const f4*>(Vin + (size_t)(row0 + r) * DD)[c];
        }
    }

    // ---- GEMM2: o = Wb + a1 @ W1
    loadW(Ww); loadB(Wb);
    __syncthreads();

    float o[2][6];
#pragma unroll
    for (int rr = 0; rr < 2; ++rr)
#pragma unroll
        for (int j = 0; j < 6; ++j) o[rr][j] = sB[c0 + j];
#pragma unroll
    for (int ch = 0; ch < 3; ++ch) {
        if (ch) {
            __syncthreads();
            loadW(Ww + ch * 32 * DD);
            __syncthreads();
        }
        const int kb = ch * 32;
#pragma unroll 4
        for (int k = 0; k < 32; ++k) {
            const float x0 = sAgg[r0 * SVP + kb + k];
            const float x1 = sAgg[(r0 + 1) * SVP + kb + k];
#pragma unroll
            for (int j = 0; j < 6; ++j) {
                const float w = sW[k * DD + c0 + j];
                o[0][j] = fmaf(x0, w, o[0][j]);
                o[1][j] = fmaf(x1, w, o[1][j]);
            }
        }
    }

    // ---- GEMM3: o += Vin @ W2
#pragma unroll
    for (int ch = 0; ch < 3; ++ch) {
        __syncthreads();
        loadW(Ww + (size_t)(96 + ch * 32) * DD);
        __syncthreads();
        const int kb = ch * 32;
#pragma unroll 4
        for (int k = 0; k < 32; ++k) {
            const float x0 = sG[r0 * SVP + kb + k];
            const float x1 = sG[(r0 + 1) * SVP + kb + k];
#pragma unroll
            for (int j = 0; j < 6; ++j) {
                const float w = sW[k * DD + c0 + j];
                o[0][j] = fmaf(x0, w, o[0][j]);
                o[1][j] = fmaf(x1, w, o[1][j]);
            }
        }
    }

#pragma unroll
    for (int rr = 0; rr < 2; ++rr) {
        const int row = row0 + r0 + rr;
        if (row < NN) {
#pragma unroll
            for (int j = 0; j < 6; ++j)
                out[(size_t)row * DD + c0 + j] = fmaxf(o[rr][j], 0.f);
        }
    }
}

// ---------------------------------------------------------------------------
extern "C" void kernel_launch(void* const* d_in, const int* in_sizes, int n_in,
                              void* d_out, int out_size, void* d_ws, size_t ws_size,
                              hipStream_t stream)
{
    const float* V   = (const float*)d_in[0];
    const float* Vin = (const float*)d_in[1];
    const float* E   = (const float*)d_in[2];
    const float* ea  = (const float*)d_in[3];
    const int*   src = (const int*)d_in[4];
    const int*   dst = (const int*)d_in[5];
    const float* Aw  = (const float*)d_in[6];
    const float* Ab  = (const float*)d_in[7];
    const float* Mw  = (const float*)d_in[8];
    const float* Mb  = (const float*)d_in[9];
    const float* Ww  = (const float*)d_in[10];
    const float* Wb  = (const float*)d_in[11];
    float* out = (float*)d_out;

    // workspace layout
    float* Vp  = (float*)d_ws;                     // NN*DD fp32
    int*   cnt = (int*)(Vp + (size_t)NN * DD);     // NN ints
    size_t aux_off = (size_t)NN * DD + NN;
    aux_off = (aux_off + 3) & ~(size_t)3;          // 16B align
    i4*    aux = (i4*)((float*)d_ws + aux_off);    // NN*CAP i4 (51.2 MB)

    hipMemsetAsync(cnt, 0, NN * sizeof(int), stream);

    // 782 blocks cover both: 782*64 >= NN rows, 782*1024 >= NE edges
    k_vpscat<<<782, 256, 0, stream>>>(V, Aw, Ab, Vp, src, dst, ea, cnt, aux);
    k_aggout<<<(NN + 31) / 32, 256, 0, stream>>>(Vp, E, cnt, aux, Vin,
                                                 Mw, Mb, Ww, Wb, out);
}